// Round 5
// baseline (640.669 us; speedup 1.0000x reference)
//
#include <hip/hip_runtime.h>

#define IN_F 4096
#define OUT_F 16384
#define MTOK 8192   // B*S

#define BM 256
#define BN 256
#define BKB 128                 // K-bytes (=elements, i8) per K-tile
#define NKT (IN_F / BKB)        // 32 K-tiles
#define NIT (NKT / 2)           // 16 iterations, 2 K-tiles each

typedef __attribute__((ext_vector_type(4)))  int   i32x4;
typedef __attribute__((ext_vector_type(16))) int   i32x16;
typedef __attribute__((ext_vector_type(4)))  float f32x4;

__device__ __forceinline__ void gload_lds16(const void* g, void* l) {
    __builtin_amdgcn_global_load_lds(
        (const __attribute__((address_space(1))) void*)g,
        (__attribute__((address_space(3))) void*)l,
        16, 0, 0);
}

// ---------------------------------------------------------------------------
// Kernel 1: per-token absmax -> int8 quantize x, store scale
// ---------------------------------------------------------------------------
__global__ __launch_bounds__(256) void k_quant(const float* __restrict__ x,
                                               char* __restrict__ xq,
                                               float* __restrict__ xs) {
    const int m = blockIdx.x;
    const int t = threadIdx.x;
    const float* xrow = x + (size_t)m * IN_F;

    f32x4 v[4];
    float mx = 0.f;
#pragma unroll
    for (int i = 0; i < 4; ++i) {
        v[i] = *(const f32x4*)&xrow[(i * 256 + t) * 4];
        mx = fmaxf(mx, fmaxf(fmaxf(fabsf(v[i].x), fabsf(v[i].y)),
                             fmaxf(fabsf(v[i].z), fabsf(v[i].w))));
    }
#pragma unroll
    for (int off = 32; off > 0; off >>= 1)
        mx = fmaxf(mx, __shfl_xor(mx, off));

    __shared__ float wmax[4];
    const int wid = t >> 6;
    if ((t & 63) == 0) wmax[wid] = mx;
    __syncthreads();
    const float scale = fmaxf(fmaxf(fmaxf(wmax[0], wmax[1]),
                                    fmaxf(wmax[2], wmax[3])), 1e-5f);
    const float inv = 127.0f / scale;

    int* xqi = (int*)(xq + (size_t)m * IN_F);
#pragma unroll
    for (int i = 0; i < 4; ++i) {
        int q0 = (int)rintf(fminf(fmaxf(v[i].x * inv, -128.f), 127.f));
        int q1 = (int)rintf(fminf(fmaxf(v[i].y * inv, -128.f), 127.f));
        int q2 = (int)rintf(fminf(fmaxf(v[i].z * inv, -128.f), 127.f));
        int q3 = (int)rintf(fminf(fmaxf(v[i].w * inv, -128.f), 127.f));
        xqi[i * 256 + t] = (q0 & 255) | ((q1 & 255) << 8) |
                           ((q2 & 255) << 16) | (q3 << 24);
    }
    if (t == 0) xs[m] = scale;
}

// ---------------------------------------------------------------------------
// Kernel 2: ternary int32 weights -> int8 pack
// ---------------------------------------------------------------------------
__global__ __launch_bounds__(256) void k_wconv(const int* __restrict__ wt,
                                               int* __restrict__ w8) {
    const int total4 = OUT_F * IN_F / 4;
    int idx = blockIdx.x * 256 + threadIdx.x;
    const int stride = gridDim.x * 256;
    for (; idx < total4; idx += stride) {
        i32x4 w = *(const i32x4*)&wt[(size_t)idx * 4];
        w8[idx] = (w.x & 255) | ((w.y & 255) << 8) |
                  ((w.z & 255) << 16) | (w.w << 24);
    }
}

// ---------------------------------------------------------------------------
// Kernel 3: i8 GEMM — 8-phase template, mfma_i32_32x32x32_i8.
// 256x256 tile, BK=128 i8, 8 waves (2Mx4N), per-wave 128x64 (4x2 32² tiles).
// LDS 128KB: A[2buf][2half][128rows][128B], B same (+64KB). Swizzle:
// phys chunk = logical ^ (row&7); staging permutes global SOURCE within each
// row's 128B only (coalescing kept). Fragment read (32x32): row=lane&31,
// kchunk = 2ks + (lane>>5), slot XOR (lane&7) -> 2-way (free) per 16-lane grp.
// Schedule/iter (buf0=tile 2t, buf1=2t+1), race-free (stage only after the
// target region's reads ended + barrier):
//  ph1 rd A-lo,B-n0      stage A1(2t+1)             MFMA(lo,n0)
//  ph2 rd B-n1           --                         MFMA(lo,n1)
//  ph3 rd A-hi           stage B0(2t+2)             MFMA(hi,n1)
//  ph4 --                stage B1,A0(2t+2)          MFMA(hi,n0)  vmcnt(6)
//  ph5-8 = same on buf1, staging A1(2t+2), B0/B1/A0(2t+3)        vmcnt(6)
// FIFO ledger: vmcnt(6) at ph4 retires exactly tile 2t+1 (read next in ph5);
// at ph8 exactly 2t+2. Last iter: vmcnt(0) (no tail stages to count).
// ---------------------------------------------------------------------------
__global__ __launch_bounds__(512, 2) void k_gemm(
    const char*  __restrict__ Aq,     // [MTOK][IN_F] int8
    const char*  __restrict__ Bq,     // [OUT_F][IN_F] int8
    const float* __restrict__ xs,     // [MTOK]
    const float* __restrict__ wsp,    // [1]
    float*       __restrict__ C) {    // [MTOK][OUT_F]
    __shared__ __align__(16) char lds[131072];   // A: 0..64K, B: 64K..128K

    const int t    = threadIdx.x;
    const int lane = t & 63;
    const int wid  = t >> 6;
    const int wr   = wid >> 2;        // 0..1  (M half)
    const int wc   = wid & 3;         // 0..3  (N quarter)

    // L2/L3-band grid mapping: XCD (bid&7) owns a bn band of 8.
    const int bid = blockIdx.x;
    const int bn  = (bid & 7) * 8 + ((bid >> 3) & 7);
    const int bm  = bid >> 6;
    const int mBase = bm * BM;
    const int nBase = bn * BN;

    // --- staging source: phys chunk pc = j*512+t; row = pc>>3,
    // src col-chunk = ((pc&7) ^ (row&7)) * 16
    const int r0 = t >> 3;
    const int c0 = ((t ^ r0) & 7) * 16;

#define STAGE_A(h, b, kt) do {                                                 \
        const size_t _s = (size_t)(mBase + (h) * 128 + r0) * IN_F + c0         \
                        + (size_t)(kt) * BKB;                                  \
        char* _d = lds + (b) * 32768 + (h) * 16384 + wid * 1024;               \
        gload_lds16(Aq + _s, _d);                                              \
        gload_lds16(Aq + _s + (size_t)64 * IN_F, _d + 8192);                   \
    } while (0)
#define STAGE_B(h, b, kt) do {                                                 \
        const size_t _s = (size_t)(nBase + (h) * 128 + r0) * IN_F + c0         \
                        + (size_t)(kt) * BKB;                                  \
        char* _d = lds + 65536 + (b) * 32768 + (h) * 16384 + wid * 1024;       \
        gload_lds16(Bq + _s, _d);                                              \
        gload_lds16(Bq + _s + (size_t)64 * IN_F, _d + 8192);                   \
    } while (0)

    // --- fragment read offsets (32x32 shape): row = lane&31,
    // logical kchunk = 2ks + h (h = lane>>5); phys = kchunk ^ (lane&7)
    const int h  = lane >> 5;
    const int r7 = lane & 7;
    int aOffKs[4], bOffKs[4];
#pragma unroll
    for (int ks = 0; ks < 4; ++ks) {
        const int slot = (((2 * ks + h) ^ r7) << 4);
        aOffKs[ks] = (lane & 31) * 128 + slot;
        bOffKs[ks] = ((wc & 1) * 64 + (lane & 31)) * 128 + slot;
    }
    const char* ldsA = lds + wr * 16384;                    // + buf*32768 + mi*4096
    const char* ldsB = lds + 65536 + (wc >> 1) * 16384;     // + buf*32768 + ni*4096

#define RD_A2(dst, bOfs, miB)                                                  \
    _Pragma("unroll")                                                          \
    for (int mi = 0; mi < 2; ++mi)                                             \
        _Pragma("unroll")                                                      \
        for (int ks = 0; ks < 4; ++ks)                                         \
            dst[mi][ks] = *(const i32x4*)(ldsA + (bOfs) +                      \
                              ((miB) + mi) * 4096 + aOffKs[ks]);
#define RD_B1(dst, bOfs, ni)                                                   \
    _Pragma("unroll")                                                          \
    for (int ks = 0; ks < 4; ++ks)                                             \
        dst[ks] = *(const i32x4*)(ldsB + (bOfs) + (ni) * 4096 + bOffKs[ks]);
#define MFMA_Q(Af, MIB, Bf, NI)                                                \
    __builtin_amdgcn_s_setprio(1);                                             \
    _Pragma("unroll")                                                          \
    for (int ks = 0; ks < 4; ++ks)                                             \
        _Pragma("unroll")                                                      \
        for (int mi = 0; mi < 2; ++mi)                                         \
            acc[(MIB) + mi][NI] = __builtin_amdgcn_mfma_i32_32x32x32_i8(       \
                Af[mi][ks], Bf[ks], acc[(MIB) + mi][NI], 0, 0, 0);             \
    __builtin_amdgcn_s_setprio(0);
#define BAR()   __builtin_amdgcn_s_barrier()
#define LGKM0() asm volatile("s_waitcnt lgkmcnt(0)" ::: "memory")
#define VM6()   asm volatile("s_waitcnt vmcnt(6)" ::: "memory")
#define VM0()   asm volatile("s_waitcnt vmcnt(0)" ::: "memory")

    i32x16 acc[4][2];
#pragma unroll
    for (int i = 0; i < 4; ++i)
#pragma unroll
        for (int j = 0; j < 2; ++j)
            acc[i][j] = (i32x16)(0);

    i32x4 aLo[2][4], aHi[2][4], b0[4], b1[4];

    // ---- prologue: tile0 fully (8 loads) + tile1 {B0,B1,A0} (6 loads)
    STAGE_A(0, 0, 0); STAGE_A(1, 0, 0); STAGE_B(0, 0, 0); STAGE_B(1, 0, 0);
    STAGE_B(0, 1, 1); STAGE_B(1, 1, 1); STAGE_A(0, 1, 1);
    VM6();           // retire tile0's 8 loads; tile1's 3 halves stay in flight
    BAR();

    for (int it = 0; it < NIT; ++it) {
        const int kt1 = 2 * it + 1;
        const int kn0 = 2 * it + 2;
        const int kn1 = 2 * it + 3;
        const bool more = (it < NIT - 1);

        // ---- ph1
        RD_A2(aLo, 0, 0); RD_B1(b0, 0, 0);
        STAGE_A(1, 1, kt1);
        BAR(); LGKM0();
        MFMA_Q(aLo, 0, b0, 0);
        BAR();
        // ---- ph2
        RD_B1(b1, 0, 1);
        BAR(); LGKM0();
        MFMA_Q(aLo, 0, b1, 1);
        BAR();
        // ---- ph3  (B reads of buf0 ended at ph2 -> safe to stage B into buf0)
        RD_A2(aHi, 0, 2);
        if (more) STAGE_B(0, 0, kn0);
        BAR(); LGKM0();
        MFMA_Q(aHi, 2, b1, 1);
        BAR();
        // ---- ph4  (A reads of buf0 ended at ph3 -> safe to stage A into buf0)
        if (more) { STAGE_B(1, 0, kn0); STAGE_A(0, 0, kn0); }
        BAR();
        MFMA_Q(aHi, 2, b0, 0);
        if (more) { VM6(); } else { VM0(); }
        BAR();
        // ---- ph5
        RD_A2(aLo, 32768, 0); RD_B1(b0, 32768, 0);
        if (more) STAGE_A(1, 0, kn0);
        BAR(); LGKM0();
        MFMA_Q(aLo, 0, b0, 0);
        BAR();
        // ---- ph6
        RD_B1(b1, 32768, 1);
        BAR(); LGKM0();
        MFMA_Q(aLo, 0, b1, 1);
        BAR();
        // ---- ph7
        RD_A2(aHi, 32768, 2);
        if (more) STAGE_B(0, 1, kn1);
        BAR(); LGKM0();
        MFMA_Q(aHi, 2, b1, 1);
        BAR();
        // ---- ph8
        if (more) { STAGE_B(1, 1, kn1); STAGE_A(0, 1, kn1); }
        BAR();
        MFMA_Q(aHi, 2, b0, 0);
        if (more) { VM6(); } else { VM0(); }
        BAR();
    }

    // ---- epilogue: 32x32 C/D map (m74/m101): col = lane&31,
    // row = (reg&3) + 8*(reg>>2) + 4*h
    const float wsc = wsp[0] * (1.0f / 127.0f);
#pragma unroll
    for (int mi = 0; mi < 4; ++mi) {
#pragma unroll
        for (int rq = 0; rq < 4; ++rq) {
            const int rowB = mBase + wr * 128 + mi * 32 + rq * 8 + h * 4;
            const f32x4 s4 = *(const f32x4*)&xs[rowB];
#pragma unroll
            for (int ni = 0; ni < 2; ++ni) {
                const int col = nBase + wc * 64 + ni * 32 + (lane & 31);
#pragma unroll
                for (int r = 0; r < 4; ++r)
                    C[(size_t)(rowB + r) * OUT_F + col] =
                        (float)acc[mi][ni][rq * 4 + r] * (s4[r] * wsc);
            }
        }
    }
}

// ---------------------------------------------------------------------------
extern "C" void kernel_launch(void* const* d_in, const int* in_sizes, int n_in,
                              void* d_out, int out_size, void* d_ws, size_t ws_size,
                              hipStream_t stream) {
    const float* x   = (const float*)d_in[0];
    const int*   wt  = (const int*)d_in[1];
    const float* wsp = (const float*)d_in[2];
    float* out = (float*)d_out;

    char*  w8 = (char*)d_ws;
    char*  xq = (char*)d_ws + (size_t)OUT_F * IN_F;
    float* xs = (float*)((char*)d_ws + (size_t)OUT_F * IN_F
                                     + (size_t)MTOK * IN_F);

    k_wconv<<<8192, 256, 0, stream>>>(wt, (int*)w8);
    k_quant<<<MTOK, 256, 0, stream>>>(x, xq, xs);

    const int grid = (MTOK / BM) * (OUT_F / BN);  // 32 * 64 = 2048
    k_gemm<<<grid, 512, 0, stream>>>(xq, w8, xs, wsp, out);
}